// Round 1
// baseline (679.806 us; speedup 1.0000x reference)
//
#include <hip/hip_runtime.h>
#include <hip/hip_bf16.h>

typedef __attribute__((ext_vector_type(8))) short bf16x8;
typedef __attribute__((ext_vector_type(4))) float f32x4;

__device__ inline ushort f2bf(float f) {
    uint u = __float_as_uint(f);
    u += 0x7fff + ((u >> 16) & 1);
    return (ushort)(u >> 16);
}
__device__ inline float bf2f(ushort h) {
    return __uint_as_float(((uint)h) << 16);
}

__device__ inline void gload16(const void* g, void* lds) {
    __builtin_amdgcn_global_load_lds(
        (const __attribute__((address_space(1))) void*)g,
        (__attribute__((address_space(3))) void*)lds, 16, 0, 0);
}

// ---------------- converts ----------------
__global__ void conv_bf16(const float* __restrict__ in, ushort* __restrict__ out, int n4) {
    int i = blockIdx.x * 256 + threadIdx.x;
    if (i >= n4) return;
    float4 a = ((const float4*)in)[i];
    ushort4 o;
    o.x = f2bf(a.x); o.y = f2bf(a.y); o.z = f2bf(a.z); o.w = f2bf(a.w);
    ((ushort4*)out)[i] = o;
}

// in: fp32 [K,N] -> out: bf16 [N,K]
__global__ void wconv_t(const float* __restrict__ in, ushort* __restrict__ out, int K, int N) {
    __shared__ float tile[32][33];
    int kb = blockIdx.y * 32, nb = blockIdx.x * 32;
    int tx = threadIdx.x & 31, ty = threadIdx.x >> 5;  // 32 x 8
#pragma unroll
    for (int i = 0; i < 4; i++)
        tile[ty + i * 8][tx] = in[(size_t)(kb + ty + i * 8) * N + nb + tx];
    __syncthreads();
#pragma unroll
    for (int i = 0; i < 4; i++) {
        int n = nb + ty + i * 8, k = kb + tx;
        out[(size_t)n * K + k] = f2bf(tile[tx][ty + i * 8]);
    }
}

// ---------------- GEMM: C = A[M,K] @ Bt[N,K]^T + bias, fused epilogues ----------------
// EPI: 0 = bf16 out; 1 = elu+1 bf16 out; 2 = relu bf16 out; 3 = fp32 out + residual
template <int EPI>
__global__ __launch_bounds__(256) void gemm_bt(
    const ushort* __restrict__ A, const ushort* __restrict__ Bt,
    const float* __restrict__ bias, const float* __restrict__ res,
    float* __restrict__ out32, ushort* __restrict__ out16,
    int M, int N, int K) {
    __shared__ ushort As[128 * 32];
    __shared__ ushort Bs[128 * 32];
    const int t = threadIdx.x;
    const int w = t >> 6, l = t & 63;
    const int wr = w >> 1, wc = w & 1;
    const int bx = blockIdx.x, by = blockIdx.y;
    f32x4 acc[4][4] = {};

    const ushort* gA = A + (size_t)(by * 128 + (t >> 2)) * K + ((t & 3) << 3);
    const ushort* gB = Bt + (size_t)(bx * 128 + (t >> 2)) * K + ((t & 3) << 3);
    ushort* ldsA = As + w * 512;  // wave-uniform base (bytes: w*1024)
    ushort* ldsB = Bs + w * 512;
    const size_t rowskip = (size_t)64 * K;

    const int nK = K >> 5;
    for (int kk = 0; kk < nK; ++kk) {
        gload16(gA, ldsA);
        gload16(gA + rowskip, ldsA + 2048);
        gload16(gB, ldsB);
        gload16(gB + rowskip, ldsB + 2048);
        gA += 32; gB += 32;
        __syncthreads();
        const int ar = wr * 64 + (l & 15);
        const int br = wc * 64 + (l & 15);
        const int ko = (l >> 4) * 8;
        bf16x8 a[4], b[4];
#pragma unroll
        for (int m = 0; m < 4; m++) a[m] = *(const bf16x8*)&As[(ar + m * 16) * 32 + ko];
#pragma unroll
        for (int n = 0; n < 4; n++) b[n] = *(const bf16x8*)&Bs[(br + n * 16) * 32 + ko];
#pragma unroll
        for (int m = 0; m < 4; m++)
#pragma unroll
            for (int n = 0; n < 4; n++)
                acc[m][n] = __builtin_amdgcn_mfma_f32_16x16x32_bf16(a[m], b[n], acc[m][n], 0, 0, 0);
        __syncthreads();
    }
    // epilogue: row = (l>>4)*4 + r, col = l&15 within each 16x16 frag
    const int row0 = by * 128 + wr * 64 + ((l >> 4) << 2);
    const int col0 = bx * 128 + wc * 64 + (l & 15);
#pragma unroll
    for (int n = 0; n < 4; n++) {
        const int col = col0 + n * 16;
        const float bv = bias[col];
#pragma unroll
        for (int m = 0; m < 4; m++) {
            const int rowb = row0 + m * 16;
#pragma unroll
            for (int r = 0; r < 4; r++) {
                float vv = acc[m][n][r] + bv;
                size_t idx = (size_t)(rowb + r) * N + col;
                if constexpr (EPI == 1) {
                    vv = vv > 0.f ? vv + 1.f : __expf(vv);
                    out16[idx] = f2bf(vv);
                } else if constexpr (EPI == 2) {
                    vv = vv > 0.f ? vv : 0.f;
                    out16[idx] = f2bf(vv);
                } else if constexpr (EPI == 3) {
                    out32[idx] = vv + res[idx];
                } else {
                    out16[idx] = f2bf(vv);
                }
            }
        }
    }
}

// ---------------- kv partial reduction ----------------
// grid: (16 chunks, 32 bh); block 256. km/v layout [B*S, 512], head cols h*64..
__global__ __launch_bounds__(256) void kv_partial(
    const ushort* __restrict__ km, const ushort* __restrict__ v,
    float* __restrict__ kvp, float* __restrict__ ksump, int S) {
    __shared__ ushort kms[32 * 64];
    __shared__ ushort vs[32 * 64];
    const int t = threadIdx.x;
    const int bh = blockIdx.y, b = bh >> 3, h = bh & 7;
    const int d0 = (t >> 4) * 4, e0 = (t & 15) * 4;
    float acc[4][4] = {};
    float ks = 0.f;
    const int s_base = blockIdx.x * 512;
    const int r = t >> 3, c8 = (t & 7) * 8;
    for (int s0 = 0; s0 < 512; s0 += 32) {
        size_t grow = ((size_t)b * S + s_base + s0 + r) * 512 + h * 64 + c8;
        *(uint4*)&kms[r * 64 + c8] = *(const uint4*)&km[grow];
        *(uint4*)&vs[r * 64 + c8] = *(const uint4*)&v[grow];
        __syncthreads();
#pragma unroll 4
        for (int s = 0; s < 32; ++s) {
            ushort4 ka = *(const ushort4*)&kms[s * 64 + d0];
            ushort4 vb = *(const ushort4*)&vs[s * 64 + e0];
            float a0 = bf2f(ka.x), a1 = bf2f(ka.y), a2 = bf2f(ka.z), a3 = bf2f(ka.w);
            float b0 = bf2f(vb.x), b1 = bf2f(vb.y), b2 = bf2f(vb.z), b3 = bf2f(vb.w);
            acc[0][0] += a0 * b0; acc[0][1] += a0 * b1; acc[0][2] += a0 * b2; acc[0][3] += a0 * b3;
            acc[1][0] += a1 * b0; acc[1][1] += a1 * b1; acc[1][2] += a1 * b2; acc[1][3] += a1 * b3;
            acc[2][0] += a2 * b0; acc[2][1] += a2 * b1; acc[2][2] += a2 * b2; acc[2][3] += a2 * b3;
            acc[3][0] += a3 * b0; acc[3][1] += a3 * b1; acc[3][2] += a3 * b2; acc[3][3] += a3 * b3;
            if (t < 64) ks += bf2f(kms[s * 64 + t]);
        }
        __syncthreads();
    }
    float* dst = kvp + ((size_t)bh * 16 + blockIdx.x) * 4096;
#pragma unroll
    for (int i = 0; i < 4; i++)
#pragma unroll
        for (int j = 0; j < 4; j++)
            dst[(d0 + i) * 64 + e0 + j] = acc[i][j];
    if (t < 64) ksump[((size_t)bh * 16 + blockIdx.x) * 64 + t] = ks;
}

__global__ void kv_reduce(const float* __restrict__ kvp, const float* __restrict__ ksump,
                          float* __restrict__ kv, float* __restrict__ ksum) {
    int i = blockIdx.x * 256 + threadIdx.x;
    if (i < 32 * 4096) {
        int bh = i >> 12, de = i & 4095;
        float s = 0.f;
#pragma unroll
        for (int c = 0; c < 16; ++c) s += kvp[((size_t)bh * 16 + c) * 4096 + de];
        kv[i] = s;
    } else {
        int j = i - 32 * 4096;
        if (j < 32 * 64) {
            int bh = j >> 6, d = j & 63;
            float s = 0.f;
#pragma unroll
            for (int c = 0; c < 16; ++c) s += ksump[((size_t)bh * 16 + c) * 64 + d];
            ksum[j] = s;
        }
    }
}

// ---------------- attn: attnE[row, h*64+e] = z * sum_d qm[d]*kv[d][e] ----------------
// grid (S/32, B), block 256 (4 waves, 8 rows each)
__global__ __launch_bounds__(256) void attn_z(
    const ushort* __restrict__ qm, const float* __restrict__ kv,
    const float* __restrict__ ksum, ushort* __restrict__ attnE, int S) {
    __shared__ ushort qrow[4][512];
    const int w = threadIdx.x >> 6, l = threadIdx.x & 63;
    const int b = blockIdx.y;
    const int row0 = blockIdx.x * 32;
    for (int i = 0; i < 8; i++) {
        int s = row0 + w * 8 + i;
        size_t rbase = ((size_t)b * S + s) * 512;
        *(uint4*)&qrow[w][l * 8] = *(const uint4*)&qm[rbase + l * 8];
        __syncthreads();
#pragma unroll
        for (int h = 0; h < 8; ++h) {
            const float* kvh = kv + ((size_t)(b * 8 + h)) * 4096;
            const float* ksh = ksum + (b * 8 + h) * 64;
            float qv = bf2f(qrow[w][h * 64 + l]);
            float den = qv * ksh[l];
#pragma unroll
            for (int o = 1; o < 64; o <<= 1) den += __shfl_xor(den, o, 64);
            float a0 = 0.f, a1 = 0.f, a2 = 0.f, a3 = 0.f;
#pragma unroll 8
            for (int d = 0; d < 64; d += 4) {
                a0 += bf2f(qrow[w][h * 64 + d + 0]) * kvh[(d + 0) * 64 + l];
                a1 += bf2f(qrow[w][h * 64 + d + 1]) * kvh[(d + 1) * 64 + l];
                a2 += bf2f(qrow[w][h * 64 + d + 2]) * kvh[(d + 2) * 64 + l];
                a3 += bf2f(qrow[w][h * 64 + d + 3]) * kvh[(d + 3) * 64 + l];
            }
            float z = 1.0f / (den + 1e-6f);
            attnE[rbase + h * 64 + l] = f2bf(((a0 + a1) + (a2 + a3)) * z);
        }
        __syncthreads();
    }
}

// ---------------- LayerNorm: wave per row of 512, optional bf16 copy ----------------
__global__ __launch_bounds__(256) void ln_kernel(
    const float* __restrict__ in, const float* __restrict__ g, const float* __restrict__ be,
    float* __restrict__ out32, ushort* __restrict__ out16, int Mrows) {
    const int w = threadIdx.x >> 6, l = threadIdx.x & 63;
    const int row = blockIdx.x * 4 + w;
    if (row >= Mrows) return;
    const float* rp = in + (size_t)row * 512;
    float4 v0 = *(const float4*)&rp[l * 8];
    float4 v1 = *(const float4*)&rp[l * 8 + 4];
    float s = v0.x + v0.y + v0.z + v0.w + v1.x + v1.y + v1.z + v1.w;
    float ss = v0.x * v0.x + v0.y * v0.y + v0.z * v0.z + v0.w * v0.w +
               v1.x * v1.x + v1.y * v1.y + v1.z * v1.z + v1.w * v1.w;
#pragma unroll
    for (int o = 1; o < 64; o <<= 1) {
        s += __shfl_xor(s, o, 64);
        ss += __shfl_xor(ss, o, 64);
    }
    float mean = s * (1.f / 512.f);
    float var = ss * (1.f / 512.f) - mean * mean;
    float rstd = rsqrtf(var + 1e-5f);
    float4 g0 = *(const float4*)&g[l * 8], g1v = *(const float4*)&g[l * 8 + 4];
    float4 b0 = *(const float4*)&be[l * 8], b1v = *(const float4*)&be[l * 8 + 4];
    float o0[8];
    o0[0] = (v0.x - mean) * rstd * g0.x + b0.x;
    o0[1] = (v0.y - mean) * rstd * g0.y + b0.y;
    o0[2] = (v0.z - mean) * rstd * g0.z + b0.z;
    o0[3] = (v0.w - mean) * rstd * g0.w + b0.w;
    o0[4] = (v1.x - mean) * rstd * g1v.x + b1v.x;
    o0[5] = (v1.y - mean) * rstd * g1v.y + b1v.y;
    o0[6] = (v1.z - mean) * rstd * g1v.z + b1v.z;
    o0[7] = (v1.w - mean) * rstd * g1v.w + b1v.w;
    float* op = out32 + (size_t)row * 512;
    *(float4*)&op[l * 8] = make_float4(o0[0], o0[1], o0[2], o0[3]);
    *(float4*)&op[l * 8 + 4] = make_float4(o0[4], o0[5], o0[6], o0[7]);
    if (out16) {
        ushort4 u0, u1;
        u0.x = f2bf(o0[0]); u0.y = f2bf(o0[1]); u0.z = f2bf(o0[2]); u0.w = f2bf(o0[3]);
        u1.x = f2bf(o0[4]); u1.y = f2bf(o0[5]); u1.z = f2bf(o0[6]); u1.w = f2bf(o0[7]);
        ushort* o16 = out16 + (size_t)row * 512;
        *(ushort4*)&o16[l * 8] = u0;
        *(ushort4*)&o16[l * 8 + 4] = u1;
    }
}

extern "C" void kernel_launch(void* const* d_in, const int* in_sizes, int n_in,
                              void* d_out, int out_size, void* d_ws, size_t ws_size,
                              hipStream_t stream) {
    const int B = 4, S = 8192, E = 512, F = 2048;
    const int M = B * S;  // 32768

    const float* src = (const float*)d_in[0];
    const float* Wq = (const float*)d_in[1];  const float* bq = (const float*)d_in[2];
    const float* Wk = (const float*)d_in[3];  const float* bk = (const float*)d_in[4];
    const float* Wv = (const float*)d_in[5];  const float* bv = (const float*)d_in[6];
    const float* Wo = (const float*)d_in[7];  const float* bo = (const float*)d_in[8];
    const float* W1 = (const float*)d_in[9];  const float* b1 = (const float*)d_in[10];
    const float* W2 = (const float*)d_in[11]; const float* b2 = (const float*)d_in[12];
    const float* g1 = (const float*)d_in[13]; const float* be1 = (const float*)d_in[14];
    const float* g2 = (const float*)d_in[15]; const float* be2 = (const float*)d_in[16];

    char* ws = (char*)d_ws;
    ushort* src16 = (ushort*)(ws + 0);               // 33.5M, later reused as attnE, then h
    ushort* qm    = (ushort*)(ws + 33554432);
    ushort* km    = (ushort*)(ws + 67108864);
    ushort* v     = (ushort*)(ws + 100663296);
    float*  kvp   = (float*)(ws + 134217728);        // 8.39M
    float*  ksump = (float*)(ws + 142606336);        // 131K
    float*  kv    = (float*)(ws + 142737408);        // 524K
    float*  ksum  = (float*)(ws + 143261696);        // 8K
    float*  x32   = (float*)(ws + 143269888);        // 67M
    ushort* x16   = (ushort*)(ws + 210378752);       // 33.5M
    ushort* wqt   = (ushort*)(ws + 243933184);
    ushort* wkt   = wqt + 262144;
    ushort* wvt   = wkt + 262144;
    ushort* wot   = wvt + 262144;
    ushort* w1t   = wot + 262144;                    // [F, E] = [2048,512]
    ushort* w2t   = w1t + 1048576;                   // [E, F] = [512,2048]
    ushort* attnE = src16;                           // alias (src16 dead after QKV)
    ushort* hbuf  = (ushort*)(ws + 0);               // alias [0,134M) (dead after Wo gemm)

    // 1) converts
    conv_bf16<<<dim3((M * E / 4 + 255) / 256), 256, 0, stream>>>(src, src16, M * E / 4);
    wconv_t<<<dim3(E / 32, E / 32), 256, 0, stream>>>(Wq, wqt, E, E);
    wconv_t<<<dim3(E / 32, E / 32), 256, 0, stream>>>(Wk, wkt, E, E);
    wconv_t<<<dim3(E / 32, E / 32), 256, 0, stream>>>(Wv, wvt, E, E);
    wconv_t<<<dim3(E / 32, E / 32), 256, 0, stream>>>(Wo, wot, E, E);
    wconv_t<<<dim3(F / 32, E / 32), 256, 0, stream>>>(W1, w1t, E, F);
    wconv_t<<<dim3(E / 32, F / 32), 256, 0, stream>>>(W2, w2t, F, E);

    // 2) QKV GEMMs with fused feature map
    gemm_bt<1><<<dim3(E / 128, M / 128), 256, 0, stream>>>(src16, wqt, bq, nullptr, nullptr, qm, M, E, E);
    gemm_bt<1><<<dim3(E / 128, M / 128), 256, 0, stream>>>(src16, wkt, bk, nullptr, nullptr, km, M, E, E);
    gemm_bt<0><<<dim3(E / 128, M / 128), 256, 0, stream>>>(src16, wvt, bv, nullptr, nullptr, v, M, E, E);

    // 3) kv / ksum reduction (deterministic two-stage)
    kv_partial<<<dim3(16, 32), 256, 0, stream>>>(km, v, kvp, ksump, S);
    kv_reduce<<<dim3((32 * 4096 + 32 * 64 + 255) / 256), 256, 0, stream>>>(kvp, ksump, kv, ksum);

    // 4) attention combine
    attn_z<<<dim3(S / 32, B), 256, 0, stream>>>(qm, kv, ksum, attnE, S);

    // 5) output proj + residual, then LN -> x32 / x16
    gemm_bt<3><<<dim3(E / 128, M / 128), 256, 0, stream>>>(attnE, wot, bo, src, x32, nullptr, M, E, E);
    ln_kernel<<<dim3(M / 4), 256, 0, stream>>>(x32, g1, be1, x32, x16, M);

    // 6) FFN
    gemm_bt<2><<<dim3(F / 128, M / 128), 256, 0, stream>>>(x16, w1t, b1, nullptr, nullptr, hbuf, M, F, E);
    gemm_bt<3><<<dim3(E / 128, M / 128), 256, 0, stream>>>(hbuf, w2t, b2, x32, (float*)d_out, nullptr, M, E, F);
    ln_kernel<<<dim3(M / 4), 256, 0, stream>>>((float*)d_out, g2, be2, (float*)d_out, nullptr, M);
}

// Round 2
// 567.504 us; speedup vs baseline: 1.1979x; 1.1979x over previous
//
#include <hip/hip_runtime.h>
#include <hip/hip_bf16.h>

typedef __attribute__((ext_vector_type(8))) short bf16x8;
typedef __attribute__((ext_vector_type(4))) float f32x4;

__device__ inline ushort f2bf(float f) {
    uint u = __float_as_uint(f);
    u += 0x7fff + ((u >> 16) & 1);
    return (ushort)(u >> 16);
}
__device__ inline float bf2f(ushort h) {
    return __uint_as_float(((uint)h) << 16);
}

__device__ inline void gload16(const void* g, void* lds) {
    __builtin_amdgcn_global_load_lds(
        (const __attribute__((address_space(1))) void*)g,
        (__attribute__((address_space(3))) void*)lds, 16, 0, 0);
}

// ---------------- converts ----------------
__global__ void conv_bf16(const float* __restrict__ in, ushort* __restrict__ out, int n4) {
    int i = blockIdx.x * 256 + threadIdx.x;
    if (i >= n4) return;
    float4 a = ((const float4*)in)[i];
    ushort4 o;
    o.x = f2bf(a.x); o.y = f2bf(a.y); o.z = f2bf(a.z); o.w = f2bf(a.w);
    ((ushort4*)out)[i] = o;
}

// in: fp32 [K,N] -> out: bf16 [N,K]
__global__ void wconv_t(const float* __restrict__ in, ushort* __restrict__ out, int K, int N) {
    __shared__ float tile[32][33];
    int kb = blockIdx.y * 32, nb = blockIdx.x * 32;
    int tx = threadIdx.x & 31, ty = threadIdx.x >> 5;  // 32 x 8
#pragma unroll
    for (int i = 0; i < 4; i++)
        tile[ty + i * 8][tx] = in[(size_t)(kb + ty + i * 8) * N + nb + tx];
    __syncthreads();
#pragma unroll
    for (int i = 0; i < 4; i++) {
        int n = nb + ty + i * 8, k = kb + tx;
        out[(size_t)n * K + k] = f2bf(tile[tx][ty + i * 8]);
    }
}

// ---------------- GEMM: C = A[M,K] @ Bt[N,K]^T + bias, fused epilogues ----------------
// EPI: 0 = bf16 out; 1 = elu+1 bf16 out; 2 = relu bf16 out; 3 = fp32 out + residual
template <int EPI>
__global__ __launch_bounds__(256) void gemm_bt(
    const ushort* __restrict__ A, const ushort* __restrict__ Bt,
    const float* __restrict__ bias, const float* __restrict__ res,
    float* __restrict__ out32, ushort* __restrict__ out16,
    int M, int N, int K) {
    __shared__ ushort As[128 * 32];
    __shared__ ushort Bs[128 * 32];
    const int t = threadIdx.x;
    const int w = t >> 6, l = t & 63;
    const int wr = w >> 1, wc = w & 1;
    const int bx = blockIdx.x, by = blockIdx.y;
    f32x4 acc[4][4] = {};

    const ushort* gA = A + (size_t)(by * 128 + (t >> 2)) * K + ((t & 3) << 3);
    const ushort* gB = Bt + (size_t)(bx * 128 + (t >> 2)) * K + ((t & 3) << 3);
    ushort* ldsA = As + w * 512;  // wave-uniform base (bytes: w*1024)
    ushort* ldsB = Bs + w * 512;
    const size_t rowskip = (size_t)64 * K;

    const int nK = K >> 5;
    for (int kk = 0; kk < nK; ++kk) {
        gload16(gA, ldsA);
        gload16(gA + rowskip, ldsA + 2048);
        gload16(gB, ldsB);
        gload16(gB + rowskip, ldsB + 2048);
        gA += 32; gB += 32;
        __syncthreads();
        const int ar = wr * 64 + (l & 15);
        const int br = wc * 64 + (l & 15);
        const int ko = (l >> 4) * 8;
        bf16x8 a[4], b[4];
#pragma unroll
        for (int m = 0; m < 4; m++) a[m] = *(const bf16x8*)&As[(ar + m * 16) * 32 + ko];
#pragma unroll
        for (int n = 0; n < 4; n++) b[n] = *(const bf16x8*)&Bs[(br + n * 16) * 32 + ko];
#pragma unroll
        for (int m = 0; m < 4; m++)
#pragma unroll
            for (int n = 0; n < 4; n++)
                acc[m][n] = __builtin_amdgcn_mfma_f32_16x16x32_bf16(a[m], b[n], acc[m][n], 0, 0, 0);
        __syncthreads();
    }
    // epilogue: row = (l>>4)*4 + r, col = l&15 within each 16x16 frag
    const int row0 = by * 128 + wr * 64 + ((l >> 4) << 2);
    const int col0 = bx * 128 + wc * 64 + (l & 15);
#pragma unroll
    for (int n = 0; n < 4; n++) {
        const int col = col0 + n * 16;
        const float bv = bias[col];
#pragma unroll
        for (int m = 0; m < 4; m++) {
            const int rowb = row0 + m * 16;
#pragma unroll
            for (int r = 0; r < 4; r++) {
                float vv = acc[m][n][r] + bv;
                size_t idx = (size_t)(rowb + r) * N + col;
                if constexpr (EPI == 1) {
                    vv = vv > 0.f ? vv + 1.f : __expf(vv);
                    out16[idx] = f2bf(vv);
                } else if constexpr (EPI == 2) {
                    vv = vv > 0.f ? vv : 0.f;
                    out16[idx] = f2bf(vv);
                } else if constexpr (EPI == 3) {
                    out32[idx] = vv + res[idx];
                } else {
                    out16[idx] = f2bf(vv);
                }
            }
        }
    }
}

// ---------------- kv partial reduction ----------------
// grid: (16 chunks, 32 bh); block 256. km/v layout [B*S, 512], head cols h*64..
__global__ __launch_bounds__(256) void kv_partial(
    const ushort* __restrict__ km, const ushort* __restrict__ v,
    float* __restrict__ kvp, float* __restrict__ ksump, int S) {
    __shared__ ushort kms[32 * 64];
    __shared__ ushort vs[32 * 64];
    const int t = threadIdx.x;
    const int bh = blockIdx.y, b = bh >> 3, h = bh & 7;
    const int d0 = (t >> 4) * 4, e0 = (t & 15) * 4;
    float acc[4][4] = {};
    float ks = 0.f;
    const int s_base = blockIdx.x * 512;
    const int r = t >> 3, c8 = (t & 7) * 8;
    for (int s0 = 0; s0 < 512; s0 += 32) {
        size_t grow = ((size_t)b * S + s_base + s0 + r) * 512 + h * 64 + c8;
        *(uint4*)&kms[r * 64 + c8] = *(const uint4*)&km[grow];
        *(uint4*)&vs[r * 64 + c8] = *(const uint4*)&v[grow];
        __syncthreads();
#pragma unroll 4
        for (int s = 0; s < 32; ++s) {
            ushort4 ka = *(const ushort4*)&kms[s * 64 + d0];
            ushort4 vb = *(const ushort4*)&vs[s * 64 + e0];
            float a0 = bf2f(ka.x), a1 = bf2f(ka.y), a2 = bf2f(ka.z), a3 = bf2f(ka.w);
            float b0 = bf2f(vb.x), b1 = bf2f(vb.y), b2 = bf2f(vb.z), b3 = bf2f(vb.w);
            acc[0][0] += a0 * b0; acc[0][1] += a0 * b1; acc[0][2] += a0 * b2; acc[0][3] += a0 * b3;
            acc[1][0] += a1 * b0; acc[1][1] += a1 * b1; acc[1][2] += a1 * b2; acc[1][3] += a1 * b3;
            acc[2][0] += a2 * b0; acc[2][1] += a2 * b1; acc[2][2] += a2 * b2; acc[2][3] += a2 * b3;
            acc[3][0] += a3 * b0; acc[3][1] += a3 * b1; acc[3][2] += a3 * b2; acc[3][3] += a3 * b3;
            if (t < 64) ks += bf2f(kms[s * 64 + t]);
        }
        __syncthreads();
    }
    float* dst = kvp + ((size_t)bh * 16 + blockIdx.x) * 4096;
#pragma unroll
    for (int i = 0; i < 4; i++)
#pragma unroll
        for (int j = 0; j < 4; j++)
            dst[(d0 + i) * 64 + e0 + j] = acc[i][j];
    if (t < 64) ksump[((size_t)bh * 16 + blockIdx.x) * 64 + t] = ks;
}

// reduce partials; kv is emitted TRANSPOSED per head as bf16: kvt[bh][e][d]
__global__ void kv_reduce(const float* __restrict__ kvp, const float* __restrict__ ksump,
                          ushort* __restrict__ kvt, float* __restrict__ ksum) {
    int i = blockIdx.x * 256 + threadIdx.x;
    if (i < 32 * 4096) {
        int bh = i >> 12, de = i & 4095;
        int d = de >> 6, e = de & 63;
        float s = 0.f;
#pragma unroll
        for (int c = 0; c < 16; ++c) s += kvp[((size_t)bh * 16 + c) * 4096 + de];
        kvt[(size_t)bh * 4096 + e * 64 + d] = f2bf(s);
    } else {
        int j = i - 32 * 4096;
        if (j < 32 * 64) {
            int bh = j >> 6, d = j & 63;
            float s = 0.f;
#pragma unroll
            for (int c = 0; c < 16; ++c) s += ksump[((size_t)bh * 16 + c) * 64 + d];
            ksum[j] = s;
        }
    }
}

// ---------------- attn via MFMA: per (b,h) attn = qm[S,64] @ kv[64,64], * z ----------------
// grid (4 col-tiles of 128 = 2 heads, M/128 row-tiles), block 256 (4 waves)
__global__ __launch_bounds__(256) void attn_mfma(
    const ushort* __restrict__ qm, const ushort* __restrict__ kvt,
    const float* __restrict__ ksum, ushort* __restrict__ attnE, int S) {
    __shared__ ushort As[128 * 128];  // 128 rows x 128 qm-cols (2 heads) = 32 KB
    __shared__ ushort Bs[128 * 64];   // 2 heads' kvt [e][d] = 16 KB
    __shared__ float zbuf[128][2];
    __shared__ float ks2[128];
    const int t = threadIdx.x, w = t >> 6, l = t & 63;
    const int cx = blockIdx.x, by = blockIdx.y;
    const int b = (by * 128) / S;
    const int h0 = cx * 2;
    const size_t arow0 = (size_t)(by * 128) * 512 + cx * 128;

    // stage As: 8 rounds x 16 rows; wave w covers rows w*4..w*4+3 each round
#pragma unroll
    for (int rd = 0; rd < 8; ++rd) {
        const ushort* g = qm + arow0 + (size_t)(rd * 16 + w * 4 + (l >> 4)) * 512 + (l & 15) * 8;
        gload16(g, (char*)As + rd * 4096 + w * 1024);
    }
    // stage Bs: 4 rounds x 32 rows (rows = e-index across 2 heads)
    const ushort* kvbase = kvt + (size_t)(b * 8 + h0) * 4096;
#pragma unroll
    for (int rd = 0; rd < 4; ++rd) {
        const ushort* g = kvbase + (rd * 32 + w * 8 + (l >> 3)) * 64 + (l & 7) * 8;
        gload16(g, (char*)Bs + rd * 4096 + w * 1024);
    }
    if (t < 128) ks2[t] = ksum[(b * 8 + h0) * 64 + t];
    __syncthreads();

    // z = 1/(qm . ksum + eps): thread t handles row t>>1, head t&1
    {
        const int r = t >> 1, hh = t & 1;
        float den = 0.f;
#pragma unroll
        for (int d0 = 0; d0 < 64; d0 += 8) {
            bf16x8 qv = *(const bf16x8*)&As[r * 128 + hh * 64 + d0];
#pragma unroll
            for (int j = 0; j < 8; j++) den += bf2f((ushort)qv[j]) * ks2[hh * 64 + d0 + j];
        }
        zbuf[r][hh] = 1.0f / (den + 1e-6f);
    }

    // MFMA: wave (wr,wc): rows wr*64.., head wc
    const int wr = w >> 1, wc = w & 1;
    const int ar = wr * 64 + (l & 15);
    const int br = wc * 64 + (l & 15);
    const int ko = (l >> 4) * 8;
    f32x4 acc[4][4] = {};
#pragma unroll
    for (int ks_ = 0; ks_ < 2; ++ks_) {
        bf16x8 a[4], bb[4];
#pragma unroll
        for (int m = 0; m < 4; m++)
            a[m] = *(const bf16x8*)&As[(ar + m * 16) * 128 + wc * 64 + ks_ * 32 + ko];
#pragma unroll
        for (int n = 0; n < 4; n++)
            bb[n] = *(const bf16x8*)&Bs[(br + n * 16) * 64 + ks_ * 32 + ko];
#pragma unroll
        for (int m = 0; m < 4; m++)
#pragma unroll
            for (int n = 0; n < 4; n++)
                acc[m][n] = __builtin_amdgcn_mfma_f32_16x16x32_bf16(a[m], bb[n], acc[m][n], 0, 0, 0);
    }
    __syncthreads();  // zbuf ready

    const int row0l = wr * 64 + ((l >> 4) << 2);
    ushort* outbase = attnE + (size_t)(by * 128) * 512 + cx * 128;
#pragma unroll
    for (int n = 0; n < 4; n++) {
#pragma unroll
        for (int m = 0; m < 4; m++) {
#pragma unroll
            for (int r = 0; r < 4; r++) {
                int rl = row0l + m * 16 + r;
                float z = zbuf[rl][wc];
                outbase[(size_t)rl * 512 + wc * 64 + n * 16 + (l & 15)] = f2bf(acc[m][n][r] * z);
            }
        }
    }
}

// ---------------- LayerNorm: wave per row of 512, optional bf16 copy ----------------
__global__ __launch_bounds__(256) void ln_kernel(
    const float* __restrict__ in, const float* __restrict__ g, const float* __restrict__ be,
    float* __restrict__ out32, ushort* __restrict__ out16, int Mrows) {
    const int w = threadIdx.x >> 6, l = threadIdx.x & 63;
    const int row = blockIdx.x * 4 + w;
    if (row >= Mrows) return;
    const float* rp = in + (size_t)row * 512;
    float4 v0 = *(const float4*)&rp[l * 8];
    float4 v1 = *(const float4*)&rp[l * 8 + 4];
    float s = v0.x + v0.y + v0.z + v0.w + v1.x + v1.y + v1.z + v1.w;
    float ss = v0.x * v0.x + v0.y * v0.y + v0.z * v0.z + v0.w * v0.w +
               v1.x * v1.x + v1.y * v1.y + v1.z * v1.z + v1.w * v1.w;
#pragma unroll
    for (int o = 1; o < 64; o <<= 1) {
        s += __shfl_xor(s, o, 64);
        ss += __shfl_xor(ss, o, 64);
    }
    float mean = s * (1.f / 512.f);
    float var = ss * (1.f / 512.f) - mean * mean;
    float rstd = rsqrtf(var + 1e-5f);
    float4 g0 = *(const float4*)&g[l * 8], g1v = *(const float4*)&g[l * 8 + 4];
    float4 b0 = *(const float4*)&be[l * 8], b1v = *(const float4*)&be[l * 8 + 4];
    float o0[8];
    o0[0] = (v0.x - mean) * rstd * g0.x + b0.x;
    o0[1] = (v0.y - mean) * rstd * g0.y + b0.y;
    o0[2] = (v0.z - mean) * rstd * g0.z + b0.z;
    o0[3] = (v0.w - mean) * rstd * g0.w + b0.w;
    o0[4] = (v1.x - mean) * rstd * g1v.x + b1v.x;
    o0[5] = (v1.y - mean) * rstd * g1v.y + b1v.y;
    o0[6] = (v1.z - mean) * rstd * g1v.z + b1v.z;
    o0[7] = (v1.w - mean) * rstd * g1v.w + b1v.w;
    float* op = out32 + (size_t)row * 512;
    *(float4*)&op[l * 8] = make_float4(o0[0], o0[1], o0[2], o0[3]);
    *(float4*)&op[l * 8 + 4] = make_float4(o0[4], o0[5], o0[6], o0[7]);
    if (out16) {
        ushort4 u0, u1;
        u0.x = f2bf(o0[0]); u0.y = f2bf(o0[1]); u0.z = f2bf(o0[2]); u0.w = f2bf(o0[3]);
        u1.x = f2bf(o0[4]); u1.y = f2bf(o0[5]); u1.z = f2bf(o0[6]); u1.w = f2bf(o0[7]);
        ushort* o16 = out16 + (size_t)row * 512;
        *(ushort4*)&o16[l * 8] = u0;
        *(ushort4*)&o16[l * 8 + 4] = u1;
    }
}

extern "C" void kernel_launch(void* const* d_in, const int* in_sizes, int n_in,
                              void* d_out, int out_size, void* d_ws, size_t ws_size,
                              hipStream_t stream) {
    const int B = 4, S = 8192, E = 512, F = 2048;
    const int M = B * S;  // 32768

    const float* src = (const float*)d_in[0];
    const float* Wq = (const float*)d_in[1];  const float* bq = (const float*)d_in[2];
    const float* Wk = (const float*)d_in[3];  const float* bk = (const float*)d_in[4];
    const float* Wv = (const float*)d_in[5];  const float* bv = (const float*)d_in[6];
    const float* Wo = (const float*)d_in[7];  const float* bo = (const float*)d_in[8];
    const float* W1 = (const float*)d_in[9];  const float* b1 = (const float*)d_in[10];
    const float* W2 = (const float*)d_in[11]; const float* b2 = (const float*)d_in[12];
    const float* g1 = (const float*)d_in[13]; const float* be1 = (const float*)d_in[14];
    const float* g2 = (const float*)d_in[15]; const float* be2 = (const float*)d_in[16];

    char* ws = (char*)d_ws;
    ushort* src16 = (ushort*)(ws + 0);               // 33.5M, later reused as attnE, then h
    ushort* qm    = (ushort*)(ws + 33554432);
    ushort* km    = (ushort*)(ws + 67108864);
    ushort* v     = (ushort*)(ws + 100663296);
    float*  kvp   = (float*)(ws + 134217728);        // 8.39M
    float*  ksump = (float*)(ws + 142606336);        // 131K
    ushort* kvt   = (ushort*)(ws + 142737408);       // 256K bf16 [32][64(e)][64(d)]
    float*  ksum  = (float*)(ws + 143261696);        // 8K
    float*  x32   = (float*)(ws + 143269888);        // 67M
    ushort* x16   = (ushort*)(ws + 210378752);       // 33.5M
    ushort* wqt   = (ushort*)(ws + 243933184);
    ushort* wkt   = wqt + 262144;
    ushort* wvt   = wkt + 262144;
    ushort* wot   = wvt + 262144;
    ushort* w1t   = wot + 262144;                    // [F, E] = [2048,512]
    ushort* w2t   = w1t + 1048576;                   // [E, F] = [512,2048]
    ushort* attnE = src16;                           // alias (src16 dead after QKV)
    ushort* hbuf  = (ushort*)(ws + 0);               // alias [0,134M) (dead after Wo gemm)

    // 1) converts
    conv_bf16<<<dim3((M * E / 4 + 255) / 256), 256, 0, stream>>>(src, src16, M * E / 4);
    wconv_t<<<dim3(E / 32, E / 32), 256, 0, stream>>>(Wq, wqt, E, E);
    wconv_t<<<dim3(E / 32, E / 32), 256, 0, stream>>>(Wk, wkt, E, E);
    wconv_t<<<dim3(E / 32, E / 32), 256, 0, stream>>>(Wv, wvt, E, E);
    wconv_t<<<dim3(E / 32, E / 32), 256, 0, stream>>>(Wo, wot, E, E);
    wconv_t<<<dim3(F / 32, E / 32), 256, 0, stream>>>(W1, w1t, E, F);
    wconv_t<<<dim3(E / 32, F / 32), 256, 0, stream>>>(W2, w2t, F, E);

    // 2) QKV GEMMs with fused feature map
    gemm_bt<1><<<dim3(E / 128, M / 128), 256, 0, stream>>>(src16, wqt, bq, nullptr, nullptr, qm, M, E, E);
    gemm_bt<1><<<dim3(E / 128, M / 128), 256, 0, stream>>>(src16, wkt, bk, nullptr, nullptr, km, M, E, E);
    gemm_bt<0><<<dim3(E / 128, M / 128), 256, 0, stream>>>(src16, wvt, bv, nullptr, nullptr, v, M, E, E);

    // 3) kv / ksum reduction (deterministic two-stage), kv emitted transposed bf16
    kv_partial<<<dim3(16, 32), 256, 0, stream>>>(km, v, kvp, ksump, S);
    kv_reduce<<<dim3((32 * 4096 + 32 * 64 + 255) / 256), 256, 0, stream>>>(kvp, ksump, kvt, ksum);

    // 4) attention combine (MFMA)
    attn_mfma<<<dim3(4, M / 128), 256, 0, stream>>>(qm, kvt, ksum, attnE, S);

    // 5) output proj + residual, then LN -> x32 / x16
    gemm_bt<3><<<dim3(E / 128, M / 128), 256, 0, stream>>>(attnE, wot, bo, src, x32, nullptr, M, E, E);
    ln_kernel<<<dim3(M / 4), 256, 0, stream>>>(x32, g1, be1, x32, x16, M);

    // 6) FFN
    gemm_bt<2><<<dim3(F / 128, M / 128), 256, 0, stream>>>(x16, w1t, b1, nullptr, nullptr, hbuf, M, F, E);
    gemm_bt<3><<<dim3(E / 128, M / 128), 256, 0, stream>>>(hbuf, w2t, b2, x32, (float*)d_out, nullptr, M, E, F);
    ln_kernel<<<dim3(M / 4), 256, 0, stream>>>((float*)d_out, g2, be2, (float*)d_out, nullptr, M);
}

// Round 3
// 461.310 us; speedup vs baseline: 1.4736x; 1.2302x over previous
//
#include <hip/hip_runtime.h>
#include <hip/hip_bf16.h>

typedef __attribute__((ext_vector_type(8))) short bf16x8;
typedef __attribute__((ext_vector_type(4))) float f32x4;

__device__ inline ushort f2bf(float f) {
    uint u = __float_as_uint(f);
    u += 0x7fff + ((u >> 16) & 1);
    return (ushort)(u >> 16);
}
__device__ inline float bf2f(ushort h) {
    return __uint_as_float(((uint)h) << 16);
}

__device__ inline void gload16(const void* g, void* lds) {
    __builtin_amdgcn_global_load_lds(
        (const __attribute__((address_space(1))) void*)g,
        (__attribute__((address_space(3))) void*)lds, 16, 0, 0);
}

// ---------------- converts ----------------
__global__ void conv_bf16(const float* __restrict__ in, ushort* __restrict__ out, int n4) {
    int i = blockIdx.x * 256 + threadIdx.x;
    if (i >= n4) return;
    float4 a = ((const float4*)in)[i];
    ushort4 o;
    o.x = f2bf(a.x); o.y = f2bf(a.y); o.z = f2bf(a.z); o.w = f2bf(a.w);
    ((ushort4*)out)[i] = o;
}

// in: fp32 [K,N] -> out: bf16 [N,K]
__global__ void wconv_t(const float* __restrict__ in, ushort* __restrict__ out, int K, int N) {
    __shared__ float tile[32][33];
    int kb = blockIdx.y * 32, nb = blockIdx.x * 32;
    int tx = threadIdx.x & 31, ty = threadIdx.x >> 5;  // 32 x 8
#pragma unroll
    for (int i = 0; i < 4; i++)
        tile[ty + i * 8][tx] = in[(size_t)(kb + ty + i * 8) * N + nb + tx];
    __syncthreads();
#pragma unroll
    for (int i = 0; i < 4; i++) {
        int n = nb + ty + i * 8, k = kb + tx;
        out[(size_t)n * K + k] = f2bf(tile[tx][ty + i * 8]);
    }
}

__global__ void biascat(const float* __restrict__ a, const float* __restrict__ b,
                        const float* __restrict__ c, float* __restrict__ o) {
    int i = blockIdx.x * 256 + threadIdx.x;
    if (i < 512) o[i] = a[i];
    else if (i < 1024) o[i] = b[i - 512];
    else if (i < 1536) o[i] = c[i - 1024];
}

// ---------------- GEMM: C = A[M,K] @ Bt[N,K]^T + bias, fused epilogues ----------------
// EPI: 0 = bf16 out; 2 = relu bf16 out; 3 = bf16 residual add + bf16 out;
//      4 = fused QKV (seg 0,1: elu+1; seg 2: plain) -> out16 as [3][M][512]
template <int EPI>
__global__ __launch_bounds__(256) void gemm_bt(
    const ushort* __restrict__ A, const ushort* __restrict__ Bt,
    const float* __restrict__ bias, const ushort* __restrict__ res16,
    ushort* __restrict__ out16,
    int M, int N, int K, int nbx) {
    __shared__ ushort As[128 * 32];
    __shared__ ushort Bs[128 * 32];
    const int t = threadIdx.x;
    const int w = t >> 6, l = t & 63;
    const int wr = w >> 1, wc = w & 1;
    // XCD-chunked bijective swizzle: blocks sharing an A-panel (same by) co-locate.
    const int nwg = gridDim.x;
    const int cpx = nwg >> 3;
    const int swz = (blockIdx.x & 7) * cpx + (blockIdx.x >> 3);
    const int bx = swz % nbx, by = swz / nbx;
    f32x4 acc[4][4] = {};

    const ushort* gA = A + (size_t)(by * 128 + (t >> 2)) * K + ((t & 3) << 3);
    const ushort* gB = Bt + (size_t)(bx * 128 + (t >> 2)) * K + ((t & 3) << 3);
    ushort* ldsA = As + w * 512;  // wave-uniform base (bytes: w*1024)
    ushort* ldsB = Bs + w * 512;
    const size_t rowskip = (size_t)64 * K;

    const int nK = K >> 5;
    for (int kk = 0; kk < nK; ++kk) {
        gload16(gA, ldsA);
        gload16(gA + rowskip, ldsA + 2048);
        gload16(gB, ldsB);
        gload16(gB + rowskip, ldsB + 2048);
        gA += 32; gB += 32;
        __syncthreads();
        const int ar = wr * 64 + (l & 15);
        const int br = wc * 64 + (l & 15);
        const int ko = (l >> 4) * 8;
        bf16x8 a[4], b[4];
#pragma unroll
        for (int m = 0; m < 4; m++) a[m] = *(const bf16x8*)&As[(ar + m * 16) * 32 + ko];
#pragma unroll
        for (int n = 0; n < 4; n++) b[n] = *(const bf16x8*)&Bs[(br + n * 16) * 32 + ko];
#pragma unroll
        for (int m = 0; m < 4; m++)
#pragma unroll
            for (int n = 0; n < 4; n++)
                acc[m][n] = __builtin_amdgcn_mfma_f32_16x16x32_bf16(a[m], b[n], acc[m][n], 0, 0, 0);
        __syncthreads();
    }
    // epilogue: row = (l>>4)*4 + r, col = l&15 within each 16x16 frag
    const int row0 = by * 128 + wr * 64 + ((l >> 4) << 2);
    const int col0 = bx * 128 + wc * 64 + (l & 15);
    const int seg = bx >> 2;  // EPI4: 512-col segment, block-uniform
    const size_t segoff = (size_t)seg * M * 512;
#pragma unroll
    for (int n = 0; n < 4; n++) {
        const int col = col0 + n * 16;
        const float bv = bias[col];
#pragma unroll
        for (int m = 0; m < 4; m++) {
            const int rowb = row0 + m * 16;
#pragma unroll
            for (int r = 0; r < 4; r++) {
                float vv = acc[m][n][r] + bv;
                size_t idx = (size_t)(rowb + r) * N + col;
                if constexpr (EPI == 2) {
                    vv = vv > 0.f ? vv : 0.f;
                    out16[idx] = f2bf(vv);
                } else if constexpr (EPI == 3) {
                    vv += bf2f(res16[idx]);
                    out16[idx] = f2bf(vv);
                } else if constexpr (EPI == 4) {
                    if (seg < 2) vv = vv > 0.f ? vv + 1.f : __expf(vv);
                    out16[segoff + (size_t)(rowb + r) * 512 + (col & 511)] = f2bf(vv);
                } else {
                    out16[idx] = f2bf(vv);
                }
            }
        }
    }
}

// ---------------- kv partial reduction ----------------
// grid: (16 chunks, 32 bh); block 256. km/v layout [B*S, 512], head cols h*64..
__global__ __launch_bounds__(256) void kv_partial(
    const ushort* __restrict__ km, const ushort* __restrict__ v,
    float* __restrict__ kvp, float* __restrict__ ksump, int S) {
    __shared__ ushort kms[32 * 64];
    __shared__ ushort vs[32 * 64];
    const int t = threadIdx.x;
    const int bh = blockIdx.y, b = bh >> 3, h = bh & 7;
    const int d0 = (t >> 4) * 4, e0 = (t & 15) * 4;
    float acc[4][4] = {};
    float ks = 0.f;
    const int s_base = blockIdx.x * 512;
    const int r = t >> 3, c8 = (t & 7) * 8;
    for (int s0 = 0; s0 < 512; s0 += 32) {
        size_t grow = ((size_t)b * S + s_base + s0 + r) * 512 + h * 64 + c8;
        *(uint4*)&kms[r * 64 + c8] = *(const uint4*)&km[grow];
        *(uint4*)&vs[r * 64 + c8] = *(const uint4*)&v[grow];
        __syncthreads();
#pragma unroll 4
        for (int s = 0; s < 32; ++s) {
            ushort4 ka = *(const ushort4*)&kms[s * 64 + d0];
            ushort4 vb = *(const ushort4*)&vs[s * 64 + e0];
            float a0 = bf2f(ka.x), a1 = bf2f(ka.y), a2 = bf2f(ka.z), a3 = bf2f(ka.w);
            float b0 = bf2f(vb.x), b1 = bf2f(vb.y), b2 = bf2f(vb.z), b3 = bf2f(vb.w);
            acc[0][0] += a0 * b0; acc[0][1] += a0 * b1; acc[0][2] += a0 * b2; acc[0][3] += a0 * b3;
            acc[1][0] += a1 * b0; acc[1][1] += a1 * b1; acc[1][2] += a1 * b2; acc[1][3] += a1 * b3;
            acc[2][0] += a2 * b0; acc[2][1] += a2 * b1; acc[2][2] += a2 * b2; acc[2][3] += a2 * b3;
            acc[3][0] += a3 * b0; acc[3][1] += a3 * b1; acc[3][2] += a3 * b2; acc[3][3] += a3 * b3;
            if (t < 64) ks += bf2f(kms[s * 64 + t]);
        }
        __syncthreads();
    }
    float* dst = kvp + ((size_t)bh * 16 + blockIdx.x) * 4096;
#pragma unroll
    for (int i = 0; i < 4; i++)
#pragma unroll
        for (int j = 0; j < 4; j++)
            dst[(d0 + i) * 64 + e0 + j] = acc[i][j];
    if (t < 64) ksump[((size_t)bh * 16 + blockIdx.x) * 64 + t] = ks;
}

// reduce partials; kv is emitted TRANSPOSED per head as bf16: kvt[bh][e][d]
__global__ void kv_reduce(const float* __restrict__ kvp, const float* __restrict__ ksump,
                          ushort* __restrict__ kvt, float* __restrict__ ksum) {
    int i = blockIdx.x * 256 + threadIdx.x;
    if (i < 32 * 4096) {
        int bh = i >> 12, de = i & 4095;
        int d = de >> 6, e = de & 63;
        float s = 0.f;
#pragma unroll
        for (int c = 0; c < 16; ++c) s += kvp[((size_t)bh * 16 + c) * 4096 + de];
        kvt[(size_t)bh * 4096 + e * 64 + d] = f2bf(s);
    } else {
        int j = i - 32 * 4096;
        if (j < 32 * 64) {
            int bh = j >> 6, d = j & 63;
            float s = 0.f;
#pragma unroll
            for (int c = 0; c < 16; ++c) s += ksump[((size_t)bh * 16 + c) * 64 + d];
            ksum[j] = s;
        }
    }
}

// ---------------- attn via MFMA: per (b,h) attn = qm[S,64] @ kv[64,64], * z ----------------
// grid (4 col-tiles of 128 = 2 heads, M/128 row-tiles), block 256 (4 waves)
__global__ __launch_bounds__(256) void attn_mfma(
    const ushort* __restrict__ qm, const ushort* __restrict__ kvt,
    const float* __restrict__ ksum, ushort* __restrict__ attnE, int S) {
    __shared__ ushort As[128 * 128];  // 128 rows x 128 qm-cols (2 heads) = 32 KB
    __shared__ ushort Bs[128 * 64];   // 2 heads' kvt [e][d] = 16 KB
    __shared__ float zbuf[128][2];
    __shared__ float ks2[128];
    const int t = threadIdx.x, w = t >> 6, l = t & 63;
    const int cx = blockIdx.x, by = blockIdx.y;
    const int b = (by * 128) / S;
    const int h0 = cx * 2;
    const size_t arow0 = (size_t)(by * 128) * 512 + cx * 128;

    // stage As: 8 rounds x 16 rows; wave w covers rows w*4..w*4+3 each round
#pragma unroll
    for (int rd = 0; rd < 8; ++rd) {
        const ushort* g = qm + arow0 + (size_t)(rd * 16 + w * 4 + (l >> 4)) * 512 + (l & 15) * 8;
        gload16(g, (char*)As + rd * 4096 + w * 1024);
    }
    // stage Bs: 4 rounds x 32 rows (rows = e-index across 2 heads)
    const ushort* kvbase = kvt + (size_t)(b * 8 + h0) * 4096;
#pragma unroll
    for (int rd = 0; rd < 4; ++rd) {
        const ushort* g = kvbase + (rd * 32 + w * 8 + (l >> 3)) * 64 + (l & 7) * 8;
        gload16(g, (char*)Bs + rd * 4096 + w * 1024);
    }
    if (t < 128) ks2[t] = ksum[(b * 8 + h0) * 64 + t];
    __syncthreads();

    // z = 1/(qm . ksum + eps): thread t handles row t>>1, head t&1
    {
        const int r = t >> 1, hh = t & 1;
        float den = 0.f;
#pragma unroll
        for (int d0 = 0; d0 < 64; d0 += 8) {
            bf16x8 qv = *(const bf16x8*)&As[r * 128 + hh * 64 + d0];
#pragma unroll
            for (int j = 0; j < 8; j++) den += bf2f((ushort)qv[j]) * ks2[hh * 64 + d0 + j];
        }
        zbuf[r][hh] = 1.0f / (den + 1e-6f);
    }

    // MFMA: wave (wr,wc): rows wr*64.., head wc
    const int wr = w >> 1, wc = w & 1;
    const int ar = wr * 64 + (l & 15);
    const int br = wc * 64 + (l & 15);
    const int ko = (l >> 4) * 8;
    f32x4 acc[4][4] = {};
#pragma unroll
    for (int ks_ = 0; ks_ < 2; ++ks_) {
        bf16x8 a[4], bb[4];
#pragma unroll
        for (int m = 0; m < 4; m++)
            a[m] = *(const bf16x8*)&As[(ar + m * 16) * 128 + wc * 64 + ks_ * 32 + ko];
#pragma unroll
        for (int n = 0; n < 4; n++)
            bb[n] = *(const bf16x8*)&Bs[(br + n * 16) * 64 + ks_ * 32 + ko];
#pragma unroll
        for (int m = 0; m < 4; m++)
#pragma unroll
            for (int n = 0; n < 4; n++)
                acc[m][n] = __builtin_amdgcn_mfma_f32_16x16x32_bf16(a[m], bb[n], acc[m][n], 0, 0, 0);
    }
    __syncthreads();  // zbuf ready

    const int row0l = wr * 64 + ((l >> 4) << 2);
    ushort* outbase = attnE + (size_t)(by * 128) * 512 + cx * 128;
#pragma unroll
    for (int n = 0; n < 4; n++) {
#pragma unroll
        for (int m = 0; m < 4; m++) {
#pragma unroll
            for (int r = 0; r < 4; r++) {
                int rl = row0l + m * 16 + r;
                float z = zbuf[rl][wc];
                outbase[(size_t)rl * 512 + wc * 64 + n * 16 + (l & 15)] = f2bf(acc[m][n][r] * z);
            }
        }
    }
}

// ---------------- LayerNorm over bf16 input: wave per row of 512 ----------------
// OUT32 = 0: bf16 out; 1: fp32 out
template <int OUT32>
__global__ __launch_bounds__(256) void ln_bf16(
    const ushort* __restrict__ in, const float* __restrict__ g, const float* __restrict__ be,
    void* __restrict__ outp, int Mrows) {
    const int w = threadIdx.x >> 6, l = threadIdx.x & 63;
    const int row = blockIdx.x * 4 + w;
    if (row >= Mrows) return;
    const ushort* rp = in + (size_t)row * 512;
    uint4 u = *(const uint4*)&rp[l * 8];
    float x[8];
    x[0] = bf2f((ushort)(u.x & 0xffff)); x[1] = bf2f((ushort)(u.x >> 16));
    x[2] = bf2f((ushort)(u.y & 0xffff)); x[3] = bf2f((ushort)(u.y >> 16));
    x[4] = bf2f((ushort)(u.z & 0xffff)); x[5] = bf2f((ushort)(u.z >> 16));
    x[6] = bf2f((ushort)(u.w & 0xffff)); x[7] = bf2f((ushort)(u.w >> 16));
    float s = 0.f, ss = 0.f;
#pragma unroll
    for (int j = 0; j < 8; j++) { s += x[j]; ss += x[j] * x[j]; }
#pragma unroll
    for (int o = 1; o < 64; o <<= 1) {
        s += __shfl_xor(s, o, 64);
        ss += __shfl_xor(ss, o, 64);
    }
    float mean = s * (1.f / 512.f);
    float var = ss * (1.f / 512.f) - mean * mean;
    float rstd = rsqrtf(var + 1e-5f);
    float4 g0 = *(const float4*)&g[l * 8], g1v = *(const float4*)&g[l * 8 + 4];
    float4 b0 = *(const float4*)&be[l * 8], b1v = *(const float4*)&be[l * 8 + 4];
    float o0[8];
    o0[0] = (x[0] - mean) * rstd * g0.x + b0.x;
    o0[1] = (x[1] - mean) * rstd * g0.y + b0.y;
    o0[2] = (x[2] - mean) * rstd * g0.z + b0.z;
    o0[3] = (x[3] - mean) * rstd * g0.w + b0.w;
    o0[4] = (x[4] - mean) * rstd * g1v.x + b1v.x;
    o0[5] = (x[5] - mean) * rstd * g1v.y + b1v.y;
    o0[6] = (x[6] - mean) * rstd * g1v.z + b1v.z;
    o0[7] = (x[7] - mean) * rstd * g1v.w + b1v.w;
    if constexpr (OUT32) {
        float* op = (float*)outp + (size_t)row * 512;
        *(float4*)&op[l * 8] = make_float4(o0[0], o0[1], o0[2], o0[3]);
        *(float4*)&op[l * 8 + 4] = make_float4(o0[4], o0[5], o0[6], o0[7]);
    } else {
        ushort* op = (ushort*)outp + (size_t)row * 512;
        ushort4 u0, u1;
        u0.x = f2bf(o0[0]); u0.y = f2bf(o0[1]); u0.z = f2bf(o0[2]); u0.w = f2bf(o0[3]);
        u1.x = f2bf(o0[4]); u1.y = f2bf(o0[5]); u1.z = f2bf(o0[6]); u1.w = f2bf(o0[7]);
        *(ushort4*)&op[l * 8] = u0;
        *(ushort4*)&op[l * 8 + 4] = u1;
    }
}

extern "C" void kernel_launch(void* const* d_in, const int* in_sizes, int n_in,
                              void* d_out, int out_size, void* d_ws, size_t ws_size,
                              hipStream_t stream) {
    const int B = 4, S = 8192, E = 512, F = 2048;
    const int M = B * S;  // 32768
    const size_t SZ = (size_t)M * E * 2;  // 32 MiB

    const float* src = (const float*)d_in[0];
    const float* Wq = (const float*)d_in[1];  const float* bq = (const float*)d_in[2];
    const float* Wk = (const float*)d_in[3];  const float* bk = (const float*)d_in[4];
    const float* Wv = (const float*)d_in[5];  const float* bv = (const float*)d_in[6];
    const float* Wo = (const float*)d_in[7];  const float* bo = (const float*)d_in[8];
    const float* W1 = (const float*)d_in[9];  const float* b1 = (const float*)d_in[10];
    const float* W2 = (const float*)d_in[11]; const float* b2 = (const float*)d_in[12];
    const float* g1 = (const float*)d_in[13]; const float* be1 = (const float*)d_in[14];
    const float* g2 = (const float*)d_in[15]; const float* be2 = (const float*)d_in[16];

    char* ws = (char*)d_ws;
    // [3][M][512] contiguous QKV block, then src16, then x16/z16; hbuf aliases 0..4*SZ
    ushort* qm    = (ushort*)(ws + 0 * SZ);
    ushort* km    = (ushort*)(ws + 1 * SZ);
    ushort* v     = (ushort*)(ws + 2 * SZ);
    ushort* src16 = (ushort*)(ws + 3 * SZ);
    ushort* x16   = (ushort*)(ws + 4 * SZ);          // alive through W2
    ushort* z16   = (ushort*)(ws + 5 * SZ);
    char*   tail  = ws + 6 * SZ;                     // 192 MiB
    float*  kvp   = (float*)(tail);                  // 8.39 MB
    float*  ksump = (float*)(tail + 8388608);        // 131 KB
    ushort* kvt   = (ushort*)(tail + 8519680);       // 256 KB
    float*  ksum  = (float*)(tail + 8781824);        // 8 KB
    float*  bqkv  = (float*)(tail + 8790016);        // 6 KB
    ushort* wqkv  = (ushort*)(tail + 8796160);       // 1.5 MB [1536,512]
    ushort* wot   = (ushort*)(tail + 10369024);      // 512 KB
    ushort* w1t   = (ushort*)(tail + 10893312);      // 2 MB [2048,512]
    ushort* w2t   = (ushort*)(tail + 12990464);      // 2 MB [512,2048]
    ushort* attnE = km;                              // km dead after kv_partial
    ushort* y16   = v;                               // v dead after kv_partial
    ushort* hbuf  = (ushort*)(ws + 0);               // [M,F] bf16, aliases 0..4*SZ

    // 1) converts
    conv_bf16<<<dim3((M * E / 4 + 255) / 256), 256, 0, stream>>>(src, src16, M * E / 4);
    wconv_t<<<dim3(E / 32, E / 32), 256, 0, stream>>>(Wq, wqkv, E, E);
    wconv_t<<<dim3(E / 32, E / 32), 256, 0, stream>>>(Wk, wqkv + 512 * 512, E, E);
    wconv_t<<<dim3(E / 32, E / 32), 256, 0, stream>>>(Wv, wqkv + 1024 * 512, E, E);
    wconv_t<<<dim3(E / 32, E / 32), 256, 0, stream>>>(Wo, wot, E, E);
    wconv_t<<<dim3(F / 32, E / 32), 256, 0, stream>>>(W1, w1t, E, F);
    wconv_t<<<dim3(E / 32, F / 32), 256, 0, stream>>>(W2, w2t, F, E);
    biascat<<<dim3(6), 256, 0, stream>>>(bq, bk, bv, bqkv);

    // 2) fused QKV GEMM (N=1536; elu+1 on q,k segments)
    gemm_bt<4><<<dim3(12 * 256), 256, 0, stream>>>(src16, wqkv, bqkv, nullptr, qm, M, 1536, E, 12);

    // 3) kv / ksum reduction (deterministic two-stage), kv emitted transposed bf16
    kv_partial<<<dim3(16, 32), 256, 0, stream>>>(km, v, kvp, ksump, S);
    kv_reduce<<<dim3((32 * 4096 + 32 * 64 + 255) / 256), 256, 0, stream>>>(kvp, ksump, kvt, ksum);

    // 4) attention combine (MFMA)
    attn_mfma<<<dim3(4, M / 128), 256, 0, stream>>>(qm, kvt, ksum, attnE, S);

    // 5) output proj + bf16 residual, then LN -> x16
    gemm_bt<3><<<dim3(4 * 256), 256, 0, stream>>>(attnE, wot, bo, src16, y16, M, E, E, 4);
    ln_bf16<0><<<dim3(M / 4), 256, 0, stream>>>(y16, g1, be1, x16, M);

    // 6) FFN
    gemm_bt<2><<<dim3(16 * 256), 256, 0, stream>>>(x16, w1t, b1, nullptr, hbuf, M, F, E, 16);
    gemm_bt<3><<<dim3(4 * 256), 256, 0, stream>>>(hbuf, w2t, b2, x16, z16, M, E, F, 4);
    ln_bf16<1><<<dim3(M / 4), 256, 0, stream>>>(z16, g2, be2, (float*)d_out, M);
}